// Round 6
// baseline (613.690 us; speedup 1.0000x reference)
//
#include <hip/hip_runtime.h>

// GCN: 3 x (GCNConv -> BN(train) -> PReLU), N=100000, E=1600000, 128->64->64->64
// R6: src-range-grouped col ordering (4 ranges of ~25K nodes = 3.2MB hsb slice)
//     so concurrently-running waves gather from an L2-resident slice.
//     R5 lesson: 4-deep MLP on a 12.8MB random-gather working set thrashed L2
//     (FETCH 90->162MB, 100->116us). Fix locality, keep MLP.
// R3 lesson: per-bucket LDS-atomic aggregation = latency disaster; register
// accumulation + big grids win.

constexpr float BN_EPS = 1e-5f;
constexpr int NB_SHIFT = 7;          // 128 nodes per bucket
constexpr int BCAP = 2560;           // pairs per bucket (avg 2048, ~11 sigma)
constexpr int PART_CHUNK = 8192;     // edges per partition block

__device__ inline float bf2f(unsigned short h) {
    return __uint_as_float(((unsigned)h) << 16);
}
__device__ inline unsigned short f2bf(float f) {
    unsigned u = __float_as_uint(f);
    unsigned r = (u + 0x7FFFu + ((u >> 16) & 1u)) >> 16;
    return (unsigned short)r;
}

// Partition edges into 128-node dst-buckets (run-contiguous pair writes).
__global__ __launch_bounds__(256) void partition_edges(
    const int* __restrict__ src, const int* __restrict__ dst,
    int* __restrict__ bcount, uint2* __restrict__ pairs, int E, int nbuck) {
    __shared__ int hist[1024];
    const int t = threadIdx.x;
    for (int i = t; i < nbuck; i += 256) hist[i] = 0;
    __syncthreads();
    const int e0 = blockIdx.x * PART_CHUNK;
    const int e1 = min(e0 + PART_CHUNK, E);
    for (int e = e0 + t; e < e1; e += 256)
        atomicAdd(&hist[dst[e] >> NB_SHIFT], 1);
    __syncthreads();
    for (int i = t; i < nbuck; i += 256) {
        int c = hist[i];
        hist[i] = (c > 0) ? atomicAdd(&bcount[i], c) : 0;  // run base within bucket
    }
    __syncthreads();
    for (int e = e0 + t; e < e1; e += 256) {
        int s = src[e], d = dst[e];
        int b = d >> NB_SHIFT;
        int pos = atomicAdd(&hist[b], 1);
        pairs[(size_t)b * BCAP + pos] = make_uint2((unsigned)s, (unsigned)d);
    }
}

// Exclusive scan of bcount[nbuck] -> bbase; also rowstart[N] = E sentinel.
__global__ __launch_bounds__(1024) void scan_bcount(
    const int* __restrict__ bcount, int* __restrict__ bbase,
    int* __restrict__ rowstart, int N, int E, int nbuck) {
    __shared__ int tmp[1024];
    const int t = threadIdx.x;
    int v = (t < nbuck) ? bcount[t] : 0;
    tmp[t] = v;
    __syncthreads();
    for (int off = 1; off < 1024; off <<= 1) {
        int u = (t >= off) ? tmp[t - off] : 0;
        __syncthreads();
        tmp[t] += u;
        __syncthreads();
    }
    if (t < nbuck) bbase[t] = tmp[t] - v;  // exclusive
    if (t == 0) rowstart[N] = E;
}

// One block per bucket: per-(node, src-range) LDS histogram -> scan ->
// rowstart/dinv, then cursor fill of col with entries of each row grouped
// by src-range (4 ranges of ~N/4 nodes = 3.2MB hsb slices for L2 locality).
__global__ __launch_bounds__(256) void fill_csr_bucket(
    const uint2* __restrict__ pairs, const int* __restrict__ bcount,
    const int* __restrict__ bbase, int* __restrict__ rowstart,
    float* __restrict__ dinv, int* __restrict__ col, int N, float rinv) {
    __shared__ int hist[512];    // (node, range) counts -> cursors
    __shared__ int ndeg[128], pfx[128];
    const int b = blockIdx.x, t = threadIdx.x;
    for (int i = t; i < 512; i += 256) hist[i] = 0;
    __syncthreads();
    const int cnt = bcount[b];
    const uint2* pp = pairs + (size_t)b * BCAP;
    for (int e = t; e < cnt; e += 256) {
        uint2 pr = pp[e];
        int rg = min(3, (int)((float)pr.x * rinv));
        atomicAdd(&hist[(int)(pr.y & 127u) * 4 + rg], 1);
    }
    __syncthreads();
    if (t < 128) {
        int d = hist[t * 4] + hist[t * 4 + 1] + hist[t * 4 + 2] + hist[t * 4 + 3];
        ndeg[t] = d;
        pfx[t] = d;
    }
    __syncthreads();
    for (int off = 1; off < 128; off <<= 1) {
        int v = 0;
        if (t < 128 && t >= off) v = pfx[t - off];
        __syncthreads();
        if (t < 128) pfx[t] += v;
        __syncthreads();
    }
    const int base = bbase[b];
    if (t < 128) {
        int deg = ndeg[t];
        int start = base + pfx[t] - deg;  // exclusive within bucket
        int n = (b << NB_SHIFT) + t;
        if (n < N) {
            rowstart[n] = start;
            dinv[n] = rsqrtf((float)deg + 1.0f);  // +1 self-loop
        }
        // convert counts to range-major cursors within the row
        int c0 = start;
        int c1 = c0 + hist[t * 4 + 0];
        int c2 = c1 + hist[t * 4 + 1];
        int c3 = c2 + hist[t * 4 + 2];
        hist[t * 4 + 0] = c0; hist[t * 4 + 1] = c1;
        hist[t * 4 + 2] = c2; hist[t * 4 + 3] = c3;
    }
    __syncthreads();
    for (int e = t; e < cnt; e += 256) {
        uint2 pr = pp[e];
        int rg = min(3, (int)((float)pr.x * rinv));
        int pos = atomicAdd(&hist[(int)(pr.y & 127u) * 4 + rg], 1);
        col[pos] = (int)pr.x;
    }
}

// hs[row][c] = (X'[row][:] @ W[:][c]) * dinv[row], stored bf16.
// FUSE: X' = prelu(X*scale + shift, a) applied per-column during staging.
template <int K, bool FUSE>
__global__ __launch_bounds__(256) void gemm_scale(
    const float* __restrict__ X, const float* __restrict__ W,
    const float* __restrict__ dinv, const float* __restrict__ stats_prev,
    const float* __restrict__ a_prev, ushort4* __restrict__ hsb4, int N) {
    static_assert(K % 64 == 0, "K must be multiple of 64");
    __shared__ float Ws[K * 64];
    __shared__ float Xs[64 * 65];

    const int t = threadIdx.x;
    const int rowBase = blockIdx.x * 64;

    for (int q = t; q < K * 16; q += 256)
        ((float4*)Ws)[q] = ((const float4*)W)[q];

    const int tx = t & 15;
    const int ty = t >> 4;

    float acc[4][4];
#pragma unroll
    for (int i = 0; i < 4; ++i)
#pragma unroll
        for (int j = 0; j < 4; ++j) acc[i][j] = 0.f;

#pragma unroll
    for (int kh = 0; kh < K / 64; ++kh) {
        __syncthreads();
#pragma unroll
        for (int j = 0; j < 4; ++j) {
            int q = t + j * 256;
            int r = q >> 4, kk = q & 15;
            int row = rowBase + r;
            float4 v = make_float4(0.f, 0.f, 0.f, 0.f);
            if (row < N) {
                v = *(const float4*)(X + (size_t)row * K + kh * 64 + kk * 4);
                if (FUSE) {
                    int cg = kh * 16 + kk;
                    float4 sc = ((const float4*)(stats_prev + 128))[cg];
                    float4 sh = ((const float4*)(stats_prev + 192))[cg];
                    float4 av = ((const float4*)a_prev)[cg];
                    v.x = fmaf(v.x, sc.x, sh.x); v.x = v.x >= 0.f ? v.x : av.x * v.x;
                    v.y = fmaf(v.y, sc.y, sh.y); v.y = v.y >= 0.f ? v.y : av.y * v.y;
                    v.z = fmaf(v.z, sc.z, sh.z); v.z = v.z >= 0.f ? v.z : av.z * v.z;
                    v.w = fmaf(v.w, sc.w, sh.w); v.w = v.w >= 0.f ? v.w : av.w * v.w;
                }
            }
            float* p = &Xs[r * 65 + kk * 4];
            p[0] = v.x; p[1] = v.y; p[2] = v.z; p[3] = v.w;
        }
        __syncthreads();
#pragma unroll 8
        for (int k = 0; k < 64; ++k) {
            float4 w4 = *(const float4*)&Ws[(kh * 64 + k) * 64 + tx * 4];
#pragma unroll
            for (int i = 0; i < 4; ++i) {
                float xv = Xs[(ty * 4 + i) * 65 + k];
                acc[i][0] = fmaf(xv, w4.x, acc[i][0]);
                acc[i][1] = fmaf(xv, w4.y, acc[i][1]);
                acc[i][2] = fmaf(xv, w4.z, acc[i][2]);
                acc[i][3] = fmaf(xv, w4.w, acc[i][3]);
            }
        }
    }

#pragma unroll
    for (int i = 0; i < 4; ++i) {
        int row = rowBase + ty * 4 + i;
        if (row < N) {
            float dv = dinv[row];
            ushort4 o;
            o.x = f2bf(acc[i][0] * dv);
            o.y = f2bf(acc[i][1] * dv);
            o.z = f2bf(acc[i][2] * dv);
            o.w = f2bf(acc[i][3] * dv);
            hsb4[(size_t)row * 16 + tx] = o;
        }
    }
}

// One wave per node: y[n] = dinv[n]*(hs[n] + sum_{src->n} hs[src]) + b
// Register accumulation, 4-deep gather MLP; fused per-feature BN stats.
// col is src-range-grouped per row: resident waves progress through 3.2MB
// hsb slices roughly in lock-step -> L2-resident gathers.
__global__ __launch_bounds__(256) void aggregate_bn(
    const ushort4* __restrict__ hsb4, const int* __restrict__ col,
    const int* __restrict__ rowstart, const float* __restrict__ dinv,
    const float* __restrict__ bias, float* __restrict__ stats,
    float4* __restrict__ y4, int N) {
    const int t = threadIdx.x;
    const int lane = t & 63;
    const int wid = t >> 6;      // wave in block (0..3)
    const int fl = lane & 15;    // float4 feature index
    const int eg = lane >> 4;    // edge subgroup (0..3)

    __shared__ float lsum[64], lsq[64];
    if (t < 64) { lsum[t] = 0.f; lsq[t] = 0.f; }
    __syncthreads();

    float4 ssum = make_float4(0.f, 0.f, 0.f, 0.f);
    float4 ssq  = make_float4(0.f, 0.f, 0.f, 0.f);
    const float4 b4 = ((const float4*)bias)[fl];
    const int waveStride = gridDim.x * 4;

    for (int n = blockIdx.x * 4 + wid; n < N; n += waveStride) {
        int start = rowstart[n];
        int deg = rowstart[n + 1] - start;
        float4 acc = make_float4(0.f, 0.f, 0.f, 0.f);
        int i = eg;
        // 4-deep MLP: 4 independent gathers in flight per lane-group
        for (; i + 12 < deg; i += 16) {
            int s0 = col[start + i];
            int s1 = col[start + i + 4];
            int s2 = col[start + i + 8];
            int s3 = col[start + i + 12];
            ushort4 r0 = hsb4[(size_t)s0 * 16 + fl];
            ushort4 r1 = hsb4[(size_t)s1 * 16 + fl];
            ushort4 r2 = hsb4[(size_t)s2 * 16 + fl];
            ushort4 r3 = hsb4[(size_t)s3 * 16 + fl];
            acc.x += (bf2f(r0.x) + bf2f(r1.x)) + (bf2f(r2.x) + bf2f(r3.x));
            acc.y += (bf2f(r0.y) + bf2f(r1.y)) + (bf2f(r2.y) + bf2f(r3.y));
            acc.z += (bf2f(r0.z) + bf2f(r1.z)) + (bf2f(r2.z) + bf2f(r3.z));
            acc.w += (bf2f(r0.w) + bf2f(r1.w)) + (bf2f(r2.w) + bf2f(r3.w));
        }
        for (; i < deg; i += 4) {
            int s = col[start + i];
            ushort4 rv = hsb4[(size_t)s * 16 + fl];
            acc.x += bf2f(rv.x); acc.y += bf2f(rv.y);
            acc.z += bf2f(rv.z); acc.w += bf2f(rv.w);
        }
        acc.x += __shfl_xor(acc.x, 16); acc.y += __shfl_xor(acc.y, 16);
        acc.z += __shfl_xor(acc.z, 16); acc.w += __shfl_xor(acc.w, 16);
        acc.x += __shfl_xor(acc.x, 32); acc.y += __shfl_xor(acc.y, 32);
        acc.z += __shfl_xor(acc.z, 32); acc.w += __shfl_xor(acc.w, 32);
        if (eg == 0) {
            ushort4 sv = hsb4[(size_t)n * 16 + fl];
            float dv = dinv[n];
            float4 yv;
            yv.x = fmaf(dv, acc.x + bf2f(sv.x), b4.x);
            yv.y = fmaf(dv, acc.y + bf2f(sv.y), b4.y);
            yv.z = fmaf(dv, acc.z + bf2f(sv.z), b4.z);
            yv.w = fmaf(dv, acc.w + bf2f(sv.w), b4.w);
            y4[(size_t)n * 16 + fl] = yv;
            ssum.x += yv.x; ssum.y += yv.y; ssum.z += yv.z; ssum.w += yv.w;
            ssq.x = fmaf(yv.x, yv.x, ssq.x); ssq.y = fmaf(yv.y, yv.y, ssq.y);
            ssq.z = fmaf(yv.z, yv.z, ssq.z); ssq.w = fmaf(yv.w, yv.w, ssq.w);
        }
    }
    if (eg == 0) {
        atomicAdd(&lsum[fl * 4 + 0], ssum.x); atomicAdd(&lsum[fl * 4 + 1], ssum.y);
        atomicAdd(&lsum[fl * 4 + 2], ssum.z); atomicAdd(&lsum[fl * 4 + 3], ssum.w);
        atomicAdd(&lsq[fl * 4 + 0], ssq.x);  atomicAdd(&lsq[fl * 4 + 1], ssq.y);
        atomicAdd(&lsq[fl * 4 + 2], ssq.z);  atomicAdd(&lsq[fl * 4 + 3], ssq.w);
    }
    __syncthreads();
    if (t < 64) atomicAdd(&stats[t], lsum[t]);
    else if (t < 128) atomicAdd(&stats[64 + (t - 64)], lsq[t - 64]);
}

__global__ void bn_final(float* __restrict__ stats, const float* __restrict__ g,
                         const float* __restrict__ be, float invN) {
    int c = threadIdx.x;  // 64 threads
    float mu = stats[c] * invN;
    float var = stats[64 + c] * invN - mu * mu;
    float sc = g[c] * rsqrtf(var + BN_EPS);
    stats[128 + c] = sc;
    stats[192 + c] = be[c] - mu * sc;
}

// final layer only: out = prelu(y*scale + shift, a)
__global__ __launch_bounds__(256) void bn_apply(
    const float4* __restrict__ y4, const float* __restrict__ stats,
    const float* __restrict__ a, float4* __restrict__ out4, int total4) {
    int i = blockIdx.x * blockDim.x + threadIdx.x;
    if (i >= total4) return;
    int cg = (i & 15) * 4;
    float4 v = y4[i];
    float4 o;
    { float z = fmaf(v.x, stats[128 + cg + 0], stats[192 + cg + 0]); o.x = z >= 0.f ? z : a[cg + 0] * z; }
    { float z = fmaf(v.y, stats[128 + cg + 1], stats[192 + cg + 1]); o.y = z >= 0.f ? z : a[cg + 1] * z; }
    { float z = fmaf(v.z, stats[128 + cg + 2], stats[192 + cg + 2]); o.z = z >= 0.f ? z : a[cg + 2] * z; }
    { float z = fmaf(v.w, stats[128 + cg + 3], stats[192 + cg + 3]); o.w = z >= 0.f ? z : a[cg + 3] * z; }
    out4[i] = o;
}

extern "C" void kernel_launch(void* const* d_in, const int* in_sizes, int n_in,
                              void* d_out, int out_size, void* d_ws, size_t ws_size,
                              hipStream_t stream) {
    const float* x  = (const float*)d_in[0];
    const int*   ei = (const int*)d_in[1];
    const int N = in_sizes[0] / 128;
    const int E = in_sizes[1] / 2;
    const int* srcp = ei;
    const int* dstp = ei + E;

    const float* W1 = (const float*)d_in[2];
    const float* b1 = (const float*)d_in[3];
    const float* g1 = (const float*)d_in[4];
    const float* be1 = (const float*)d_in[5];
    const float* a1 = (const float*)d_in[6];
    const float* W2 = (const float*)d_in[7];
    const float* b2 = (const float*)d_in[8];
    const float* g2 = (const float*)d_in[9];
    const float* be2 = (const float*)d_in[10];
    const float* a2 = (const float*)d_in[11];
    const float* W3 = (const float*)d_in[12];
    const float* b3 = (const float*)d_in[13];
    const float* g3 = (const float*)d_in[14];
    const float* be3 = (const float*)d_in[15];
    const float* a3 = (const float*)d_in[16];

    const int nbuck = (N + 127) >> NB_SHIFT;  // 782
    const int rdiv = (N + 3) / 4;             // src-range width (~25000)
    const float rinv = 1.0f / (float)rdiv;

    // ws layout (4B units):
    // dinv[N] | rowstart[N+4] | bcount[1024] | bbase[1024] | stats[768] |
    // col[E] | pairs[nbuck*BCAP*2] | hsb[N*32] | ybuf[N*64]
    float* ws = (float*)d_ws;
    float* dinv     = ws;
    int*   rowstart = (int*)(ws + N);
    int*   bcount   = (int*)(ws + 2 * (size_t)N + 4);
    int*   bbase    = bcount + 1024;
    float* stats    = (float*)(bbase + 1024);
    int*   col      = (int*)(stats + 768);
    uint2* pairs    = (uint2*)(col + E);
    float* hsbf     = (float*)(pairs + (size_t)nbuck * BCAP);
    ushort4* hsb4   = (ushort4*)hsbf;
    float* ybuf     = hsbf + (size_t)N * 32;

    float* stats1 = stats, *stats2 = stats + 256, *stats3 = stats + 512;

    // one memset covers bcount + bbase + stats (contiguous)
    hipMemsetAsync(bcount, 0, (1024 + 1024 + 768) * sizeof(int), stream);
    partition_edges<<<(E + PART_CHUNK - 1) / PART_CHUNK, 256, 0, stream>>>(
        srcp, dstp, bcount, pairs, E, nbuck);
    scan_bcount<<<1, 1024, 0, stream>>>(bcount, bbase, rowstart, N, E, nbuck);
    fill_csr_bucket<<<nbuck, 256, 0, stream>>>(pairs, bcount, bbase, rowstart,
                                               dinv, col, N, rinv);

    const int gemmGrid = (N + 63) / 64;
    const int aggGrid = 2048;
    const int applyGrid = (N * 16 + 255) / 256;
    const float invN = 1.0f / (float)N;

    // ---- layer 1 ----
    gemm_scale<128, false><<<gemmGrid, 256, 0, stream>>>(x, W1, dinv, nullptr, nullptr, hsb4, N);
    aggregate_bn<<<aggGrid, 256, 0, stream>>>(hsb4, col, rowstart, dinv, b1,
                                              stats1, (float4*)ybuf, N);
    bn_final<<<1, 64, 0, stream>>>(stats1, g1, be1, invN);

    // ---- layer 2 (BN1+PReLU1 fused into X staging) ----
    gemm_scale<64, true><<<gemmGrid, 256, 0, stream>>>(ybuf, W2, dinv, stats1, a1, hsb4, N);
    aggregate_bn<<<aggGrid, 256, 0, stream>>>(hsb4, col, rowstart, dinv, b2,
                                              stats2, (float4*)ybuf, N);
    bn_final<<<1, 64, 0, stream>>>(stats2, g2, be2, invN);

    // ---- layer 3 ----
    gemm_scale<64, true><<<gemmGrid, 256, 0, stream>>>(ybuf, W3, dinv, stats2, a2, hsb4, N);
    aggregate_bn<<<aggGrid, 256, 0, stream>>>(hsb4, col, rowstart, dinv, b3,
                                              stats3, (float4*)ybuf, N);
    bn_final<<<1, 64, 0, stream>>>(stats3, g3, be3, invN);

    bn_apply<<<applyGrid, 256, 0, stream>>>((const float4*)ybuf, stats3, a3,
                                            (float4*)d_out, N * 16);
}